// Round 3
// baseline (365.109 us; speedup 1.0000x reference)
//
#include <hip/hip_runtime.h>

#define NN 50000
#define NE 800000
#define NH 64
#define NG 500
#define NPAD 50176   // 196*256
#define NBKT 782     // ceil(NN/64) 64-node buckets
#define CAP 1536     // padded bucket capacity (max bucket deg ~1130; 4.5+ sigma margin)
#define ZR NN        // dedicated zero row in hWbf (zeroed once in k_prep)

typedef __attribute__((ext_vector_type(8))) short bf16x8;   // 8 bf16 = 4 VGPR (MFMA A/B frag)
typedef __attribute__((ext_vector_type(4))) float f32x4;    // MFMA C/D frag

// fp32 -> bf16 round-to-nearest-even
__device__ __forceinline__ unsigned short f2bf(float f) {
  unsigned x = __float_as_uint(f);
  unsigned r = ((x >> 16) & 1u) + 0x7fffu;
  return (unsigned short)((x + r) >> 16);
}
__device__ __forceinline__ float bf2f(unsigned short u) {
  return __uint_as_float(((unsigned)u) << 16);
}

// ---------------- prep: W fragments + zero bcur/out/ZR-row (folds the old memset + pool-zero) ----------------
// Fragment convention (16x16x32 bf16): lane = (idx&15) + 16*kb; element e <-> k = s*32 + kb*8 + e.
// fid = mat*16 + part*8 + s*4 + ntile; mat: 0=conv 1=res; part: 0=bf16-hi 1=bf16-lo.

__global__ __launch_bounds__(256) void k_prep(const float* __restrict__ Wc, const float* __restrict__ Wr,
                                              unsigned short* __restrict__ Wf,
                                              int* __restrict__ bcur, float* __restrict__ out,
                                              unsigned short* __restrict__ hWbf) {
  if (blockIdx.x == 8) {
    int tt = threadIdx.x;
    for (int i = tt; i < 1024; i += 256) bcur[i] = 0;
    for (int i = tt; i < NG; i += 256) out[i] = 0.f;
    if (tt < 32) ((unsigned*)(hWbf + (size_t)ZR * 64))[tt] = 0u;
    return;
  }
  int t = blockIdx.x * 256 + threadIdx.x;   // 2048 threads = 32 frags * 64 lanes
  int fid = t >> 6;
  int lane = t & 63;
  int ntile = fid & 3, s = (fid >> 2) & 1, part = (fid >> 3) & 1, mat = fid >> 4;
  const float* W = mat ? Wr : Wc;
  int col = ntile * 16 + (lane & 15);
  int k0 = s * 32 + (lane >> 4) * 8;
#pragma unroll
  for (int e = 0; e < 8; e++) {
    float w = W[(k0 + e) * 64 + col];
    unsigned short h = f2bf(w);
    Wf[(size_t)fid * 512 + lane * 8 + e] = part ? f2bf(w - bf2f(h)) : h;
  }
}

// ---------------- binning into padded buckets: colp[b*CAP + r] ----------------

__global__ __launch_bounds__(256) void k_bin(const int* __restrict__ src, const int* __restrict__ dst,
                                             int* __restrict__ bcur, int* __restrict__ colp) {
  __shared__ int hist[NBKT];
  __shared__ int gbase[NBKT];
  int t = threadIdx.x;
  for (int b = t; b < NBKT; b += 256) hist[b] = 0;
  __syncthreads();
  int e0 = blockIdx.x * 8192;
#pragma unroll
  for (int i = 0; i < 32; i++) {
    int e = e0 + i * 256 + t;
    if (e < NE) atomicAdd(&hist[dst[e] >> 6], 1);
  }
  __syncthreads();
  for (int b = t; b < NBKT; b += 256) {
    int c = hist[b];
    gbase[b] = c ? atomicAdd(&bcur[b], c) : 0;
    hist[b] = 0;  // reuse as rank counter
  }
  __syncthreads();
#pragma unroll
  for (int i = 0; i < 32; i++) {
    int e = e0 + i * 256 + t;
    if (e < NE) {
      int s = src[e], d = dst[e];
      int b = d >> 6;
      int r = atomicAdd(&hist[b], 1);
      colp[b * CAP + gbase[b] + r] = (s << 6) | (d & 63);
    }
  }
}

// ---------------- shared gemm tile body (MFMA, LDS-free, split-bf16) ----------------
// MODE 0: X = Xin. MODE 1: X = relu(Xin + dinv[n]*bf2f(gsum[n])).

template <int MODE>
__device__ __forceinline__ void gemm_tile(int lane, int n0,
                                          const float* __restrict__ Xin,
                                          const unsigned short* __restrict__ gsum,
                                          const unsigned short* __restrict__ Wf,
                                          const float* __restrict__ cb, const float* __restrict__ rb,
                                          const float* __restrict__ dinv,
                                          unsigned short* __restrict__ hWout, float* __restrict__ agg) {
  int col16 = lane & 15;
  int kb = lane >> 4;
  int nr = n0 + col16;
  int nc = nr < NN ? nr : NN - 1;   // clamp loads; garbage rows never stored
  const float* xrow = Xin + (size_t)nc * 64;
  float v0[8], v1[8];
  {
    float4 a = *(const float4*)(xrow + kb * 8);
    float4 b4 = *(const float4*)(xrow + kb * 8 + 4);
    float4 c = *(const float4*)(xrow + 32 + kb * 8);
    float4 d = *(const float4*)(xrow + 32 + kb * 8 + 4);
    v0[0] = a.x; v0[1] = a.y; v0[2] = a.z; v0[3] = a.w;
    v0[4] = b4.x; v0[5] = b4.y; v0[6] = b4.z; v0[7] = b4.w;
    v1[0] = c.x; v1[1] = c.y; v1[2] = c.z; v1[3] = c.w;
    v1[4] = d.x; v1[5] = d.y; v1[6] = d.z; v1[7] = d.w;
  }
  if (MODE) {
    float dvn = dinv[nc];
    const unsigned* grow = (const unsigned*)(gsum + (size_t)nc * 64);
    uint4 g0 = *(const uint4*)(grow + kb * 4);
    uint4 g1 = *(const uint4*)(grow + 16 + kb * 4);
    unsigned ga[4] = {g0.x, g0.y, g0.z, g0.w};
    unsigned gb[4] = {g1.x, g1.y, g1.z, g1.w};
#pragma unroll
    for (int e = 0; e < 4; e++) {
      v0[2 * e]     = fmaxf(v0[2 * e]     + dvn * bf2f((unsigned short)(ga[e] & 0xffff)), 0.f);
      v0[2 * e + 1] = fmaxf(v0[2 * e + 1] + dvn * bf2f((unsigned short)(ga[e] >> 16)), 0.f);
      v1[2 * e]     = fmaxf(v1[2 * e]     + dvn * bf2f((unsigned short)(gb[e] & 0xffff)), 0.f);
      v1[2 * e + 1] = fmaxf(v1[2 * e + 1] + dvn * bf2f((unsigned short)(gb[e] >> 16)), 0.f);
    }
  }
  bf16x8 ah0, al0, ah1, al1;
#pragma unroll
  for (int e = 0; e < 8; e++) {
    unsigned short h0 = f2bf(v0[e]);
    ah0[e] = (short)h0;
    al0[e] = (short)f2bf(v0[e] - bf2f(h0));
    unsigned short h1 = f2bf(v1[e]);
    ah1[e] = (short)h1;
    al1[e] = (short)f2bf(v1[e] - bf2f(h1));
  }

  f32x4 aC[4], aR[4];
#pragma unroll
  for (int j = 0; j < 4; j++) {
    aC[j] = (f32x4){0.f, 0.f, 0.f, 0.f};
    aR[j] = (f32x4){0.f, 0.f, 0.f, 0.f};
  }
  const bf16x8* WFv = (const bf16x8*)Wf;
#pragma unroll
  for (int j = 0; j < 4; j++) {
    bf16x8 wch0 = WFv[(j)      * 64 + lane];
    bf16x8 wch1 = WFv[(4 + j)  * 64 + lane];
    bf16x8 wcl0 = WFv[(8 + j)  * 64 + lane];
    bf16x8 wcl1 = WFv[(12 + j) * 64 + lane];
    bf16x8 wrh0 = WFv[(16 + j) * 64 + lane];
    bf16x8 wrh1 = WFv[(20 + j) * 64 + lane];
    bf16x8 wrl0 = WFv[(24 + j) * 64 + lane];
    bf16x8 wrl1 = WFv[(28 + j) * 64 + lane];
    f32x4 c = aC[j];
    c = __builtin_amdgcn_mfma_f32_16x16x32_bf16(ah0, wch0, c, 0, 0, 0);
    c = __builtin_amdgcn_mfma_f32_16x16x32_bf16(ah1, wch1, c, 0, 0, 0);
    c = __builtin_amdgcn_mfma_f32_16x16x32_bf16(al0, wch0, c, 0, 0, 0);
    c = __builtin_amdgcn_mfma_f32_16x16x32_bf16(al1, wch1, c, 0, 0, 0);
    c = __builtin_amdgcn_mfma_f32_16x16x32_bf16(ah0, wcl0, c, 0, 0, 0);
    c = __builtin_amdgcn_mfma_f32_16x16x32_bf16(ah1, wcl1, c, 0, 0, 0);
    aC[j] = c;
    f32x4 r = aR[j];
    r = __builtin_amdgcn_mfma_f32_16x16x32_bf16(ah0, wrh0, r, 0, 0, 0);
    r = __builtin_amdgcn_mfma_f32_16x16x32_bf16(ah1, wrh1, r, 0, 0, 0);
    r = __builtin_amdgcn_mfma_f32_16x16x32_bf16(al0, wrh0, r, 0, 0, 0);
    r = __builtin_amdgcn_mfma_f32_16x16x32_bf16(al1, wrh1, r, 0, 0, 0);
    r = __builtin_amdgcn_mfma_f32_16x16x32_bf16(ah0, wrl0, r, 0, 0, 0);
    r = __builtin_amdgcn_mfma_f32_16x16x32_bf16(ah1, wrl1, r, 0, 0, 0);
    aR[j] = r;
  }

  // epilogue: D layout col=lane&15, row=(lane>>4)*4+reg
  float cbv[4], rbv[4];
#pragma unroll
  for (int j = 0; j < 4; j++) {
    cbv[j] = cb[j * 16 + col16];
    rbv[j] = rb[j * 16 + col16];
  }
  int rbase = kb * 4;
#pragma unroll
  for (int r = 0; r < 4; r++) {
    int node = n0 + rbase + r;
    if (node < NN) {
      float dv = dinv[node];
      size_t o = (size_t)node * 64 + col16;
#pragma unroll
      for (int j = 0; j < 4; j++) {
        float hc = dv * aC[j][r];
        unsigned short hb = f2bf(hc);
        hWout[o + j * 16] = hb;
        agg[o + j * 16] = aR[j][r] + rbv[j] + cbv[j] + dv * hc;
      }
    }
  }
}

// ---------------- fused: bucket CSR + encoder + gemm0 (block b = bucket b, 64 nodes) ----------------

__global__ __launch_bounds__(256) void k_csr_enc_g0(const int* __restrict__ bcur, const int* __restrict__ colp,
                                                    int* __restrict__ cols, float* __restrict__ dinv,
                                                    int* __restrict__ rowst, int* __restrict__ rowen,
                                                    const float* __restrict__ x, const float* __restrict__ pos,
                                                    const float* __restrict__ encW, const float* __restrict__ encb,
                                                    const unsigned short* __restrict__ Wf,
                                                    const float* __restrict__ cb, const float* __restrict__ rb,
                                                    unsigned short* __restrict__ hWout,
                                                    float* __restrict__ X0, float* __restrict__ agg) {
  __shared__ int hist[64];
  __shared__ int excl[65];
  __shared__ float Ws[16 * 64];
  __shared__ float bs[64];
  int t = threadIdx.x;
  int b = blockIdx.x;

  for (int i = t; i < 1024; i += 256) Ws[i] = encW[i];
  if (t < 64) bs[t] = encb[t];

  int base = b * CAP;
  int cnt = bcur[b];
  if (t < 64) hist[t] = 0;
  __syncthreads();
  for (int e = t; e < cnt; e += 256) atomicAdd(&hist[colp[base + e] & 63], 1);
  __syncthreads();
  if (t == 0) {
    int run = 0;
#pragma unroll
    for (int i = 0; i < 64; i++) { excl[i] = run; run += hist[i]; }
    excl[64] = run;
  }
  __syncthreads();
  if (t < 64) {
    int n = b * 64 + t;
    rowst[n] = base + excl[t];
    rowen[n] = base + excl[t + 1];
    if (n < NN) dinv[n] = rsqrtf((float)(hist[t] + 1));  // +1 self-loop
    hist[t] = 0;  // reuse as cursor
  }
  __syncthreads();
  for (int e = t; e < cnt; e += 256) {
    int w = colp[base + e];
    int d = w & 63;
    int r = atomicAdd(&hist[d], 1);
    cols[base + excl[d] + r] = w >> 6;
  }

  // encoder for this bucket's 64 rows (disjoint from cols scatter; barrier below covers both)
  int h = t & 63;
  int nset = t >> 6;
#pragma unroll
  for (int i = 0; i < 16; i++) {
    int n = b * 64 + nset * 16 + i;
    if (n < NN) {
      const float* xr = x + n * 14;
      float acc = bs[h];
#pragma unroll
      for (int f = 0; f < 14; f++) acc += xr[f] * Ws[f * 64 + h];
      acc += pos[n * 2 + 0] * Ws[14 * 64 + h];
      acc += pos[n * 2 + 1] * Ws[15 * 64 + h];
      X0[(size_t)n * 64 + h] = acc;
    }
  }
  __syncthreads();  // X0 + dinv visible block-wide (same CU)

  // gemm0 (mode 0): 4 waves x 16 rows x 64 cols
  gemm_tile<0>(t & 63, b * 64 + (t >> 6) * 16, X0, (const unsigned short*)0, Wf, cb, rb, dinv, hWout, agg);
}

// ---------------- standalone gemm (mode 1), layers 1..4 ----------------

__global__ __launch_bounds__(256) void k_gemm(const float* __restrict__ Xin,
                                              const unsigned short* __restrict__ gsum,
                                              const unsigned short* __restrict__ Wf,
                                              const float* __restrict__ cb, const float* __restrict__ rb,
                                              const float* __restrict__ dinv,
                                              unsigned short* __restrict__ hWout, float* __restrict__ agg) {
  gemm_tile<1>(threadIdx.x & 63, blockIdx.x * 64 + (threadIdx.x >> 6) * 16,
               Xin, gsum, Wf, cb, rb, dinv, hWout, agg);
}

// ---------------- gather core: one node per wave, BATCHED loads (8 in flight) ----------------
// lane = (p = lane>>5, h2 = lane&31): h-pair 2*h2, 2*h2+1 of edge-pair-member p. Straight-line
// per 16-edge group: 8 shfl -> 8 ZR-selects -> 8 loads -> 16 adds, so all 8 row-loads are
// outstanding under one vmcnt round (the R2 macro interleaved load+add per edge -> 8 serial
// latency rounds -> the 96 us gather_final).

__device__ __forceinline__ void gather_node(int n, int lane, int h2, int p,
                                            const int* __restrict__ rowst, const int* __restrict__ rowen,
                                            const int* __restrict__ cols, const unsigned* __restrict__ hW32,
                                            float& a0, float& a1) {
  int st = rowst[n];
  int en = rowen[n];
  int deg = en - st;
  a0 = 0.f; a1 = 0.f;
  for (int base2 = 0; base2 < deg; base2 += 64) {
    int cnt = deg - base2;
    if (cnt > 64) cnt = 64;
    int li = lane < cnt ? lane : cnt - 1;
    int colv = cols[st + base2 + li];  // one coalesced load of up to 64 indices
    for (int j = 0; j < cnt; j += 16) {
      int sx[8];
#pragma unroll
      for (int k2 = 0; k2 < 8; k2++) {
        int e = j + 2 * k2 + p;
        int s = __shfl(colv, e, 64);
        sx[k2] = e < cnt ? s : ZR;   // padding -> dedicated zero row (one hot line)
      }
      unsigned ux[8];
#pragma unroll
      for (int k2 = 0; k2 < 8; k2++) ux[k2] = hW32[(unsigned)sx[k2] * 32u + (unsigned)h2];
#pragma unroll
      for (int k2 = 0; k2 < 8; k2++) {
        a0 += __uint_as_float(ux[k2] << 16);
        a1 += __uint_as_float(ux[k2] & 0xffff0000u);
      }
    }
  }
  a0 += __shfl_down(a0, 32, 64);
  a1 += __shfl_down(a1, 32, 64);
}

// ---------------- gather layers 0..3: hW -> gsum ----------------

__global__ __launch_bounds__(256) void k_gather(const int* __restrict__ rowst, const int* __restrict__ rowen,
                                                const int* __restrict__ cols,
                                                const unsigned short* __restrict__ hWin,
                                                unsigned short* __restrict__ gsum) {
  int lane = threadIdx.x & 63;
  int h2 = lane & 31;
  int p = lane >> 5;
  int n = __builtin_amdgcn_readfirstlane(blockIdx.x * 4 + (threadIdx.x >> 6));
  float a0, a1;
  gather_node(n, lane, h2, p, rowst, rowen, cols, (const unsigned*)hWin, a0, a1);
  if (lane < 32)
    ((unsigned*)gsum)[(unsigned)n * 32u + (unsigned)h2] = (unsigned)f2bf(a0) | ((unsigned)f2bf(a1) << 16);
}

// ---------------- final gather + decode + atomic pool ----------------

__global__ __launch_bounds__(256) void k_gather_final(const int* __restrict__ rowst, const int* __restrict__ rowen,
                                                      const int* __restrict__ cols,
                                                      const unsigned short* __restrict__ hWin,
                                                      const float* __restrict__ aggIn, const float* __restrict__ dinv,
                                                      const float* __restrict__ decW, const float* __restrict__ decb,
                                                      const int* __restrict__ batch, float* __restrict__ out) {
  int lane = threadIdx.x & 63;
  int h2 = lane & 31;
  int p = lane >> 5;
  int n = __builtin_amdgcn_readfirstlane(blockIdx.x * 4 + (threadIdx.x >> 6));
  float a0, a1;
  gather_node(n, lane, h2, p, rowst, rowen, cols, (const unsigned*)hWin, a0, a1);
  float dv = dinv[n];
  float2 ag = *(const float2*)(aggIn + (size_t)n * 64 + h2 * 2);  // valid addr for all lanes
  float v = fmaxf(ag.x + dv * a0, 0.f) * decW[h2 * 2] + fmaxf(ag.y + dv * a1, 0.f) * decW[h2 * 2 + 1];
  v = (lane < 32) ? v : 0.f;  // upper half holds stale partials -> zero them
#pragma unroll
  for (int off = 32; off > 0; off >>= 1) v += __shfl_down(v, off, 64);
  if (lane == 0) atomicAdd(&out[batch[n]], v + decb[0]);
}

// ---------------- launch: 12 dispatches ----------------

extern "C" void kernel_launch(void* const* d_in, const int* in_sizes, int n_in,
                              void* d_out, int out_size, void* d_ws, size_t ws_size,
                              hipStream_t stream) {
  (void)in_sizes; (void)n_in; (void)out_size; (void)ws_size;
  const float* x     = (const float*)d_in[0];
  const float* pos   = (const float*)d_in[1];
  const int*   ei    = (const int*)d_in[2];
  const int*   batch = (const int*)d_in[3];
  const float* encW  = (const float*)d_in[4];
  const float* encb  = (const float*)d_in[5];
  const float* convW = (const float*)d_in[6];
  const float* convb = (const float*)d_in[7];
  const float* resW  = (const float*)d_in[8];
  const float* resb  = (const float*)d_in[9];
  const float* decW  = (const float*)d_in[10];
  const float* decb  = (const float*)d_in[11];
  float* out = (float*)d_out;

  const int* src = ei;       // edge_index[0]
  const int* dst = ei + NE;  // edge_index[1]

  // workspace layout (4-byte elems)
  float*          ws    = (float*)d_ws;
  float*          dinv  = ws;                                    // [NPAD]
  int*            rowst = (int*)(ws + NPAD);                     // [NPAD]
  int*            rowen = (int*)(ws + 2 * NPAD);                 // [NPAD]
  int*            bcur  = (int*)(ws + 3 * NPAD);                 // [1024]
  int*            colp  = bcur + 1024;                           // [NBKT*CAP]
  int*            cols  = colp + NBKT * CAP;                     // [NBKT*CAP]
  unsigned short* hWbf  = (unsigned short*)(cols + NBKT * CAP);  // [NPAD*64] bf16
  unsigned short* gsum  = hWbf + (size_t)NPAD * 64;              // [NPAD*64] bf16
  float*          bufA  = (float*)(gsum + (size_t)NPAD * 64);    // [NN*NH]
  float*          bufB  = bufA + NN * NH;                        // [NN*NH]
  unsigned short* Wf    = (unsigned short*)(bufB + NN * NH);     // [32*512] bf16 frag W

  k_prep<<<9, 256, 0, stream>>>(convW, resW, Wf, bcur, out, hWbf);
  k_bin<<<(NE + 8191) / 8192, 256, 0, stream>>>(src, dst, bcur, colp);
  k_csr_enc_g0<<<NBKT, 256, 0, stream>>>(bcur, colp, cols, dinv, rowst, rowen,
                                         x, pos, encW, encb, Wf, convb, resb,
                                         hWbf, bufA, bufB);
  // layers: gather hW_l -> gsum; gemm mode1 -> hW_{l+1}, agg ping-pong (B->A->B->A->B)
  float* aggIn = bufB;
  float* aggOut = bufA;
  for (int l = 0; l < 4; l++) {
    k_gather<<<NN / 4, 256, 0, stream>>>(rowst, rowen, cols, hWbf, gsum);
    k_gemm<<<NBKT, 256, 0, stream>>>(aggIn, gsum, Wf, convb, resb, dinv, hWbf, aggOut);
    float* tmp = aggIn; aggIn = aggOut; aggOut = tmp;
  }
  k_gather_final<<<NN / 4, 256, 0, stream>>>(rowst, rowen, cols, hWbf, aggIn, dinv, decW, decb, batch, out);
}

// Round 4
// 276.962 us; speedup vs baseline: 1.3183x; 1.3183x over previous
//
#include <hip/hip_runtime.h>

#define NN 50000
#define NE 800000
#define NH 64
#define NG 500
#define NPAD 50176   // 196*256
#define NBKT 782     // ceil(NN/64) 64-node buckets
#define CAP 1536     // padded bucket capacity (max bucket deg ~1130; 4.5+ sigma margin)
#define ZR NN        // dedicated zero row in hWbf (zeroed once in k_prep)

typedef __attribute__((ext_vector_type(8))) short bf16x8;   // 8 bf16 = 4 VGPR (MFMA A/B frag)
typedef __attribute__((ext_vector_type(4))) float f32x4;    // MFMA C/D frag

// fp32 -> bf16 round-to-nearest-even
__device__ __forceinline__ unsigned short f2bf(float f) {
  unsigned x = __float_as_uint(f);
  unsigned r = ((x >> 16) & 1u) + 0x7fffu;
  return (unsigned short)((x + r) >> 16);
}
__device__ __forceinline__ float bf2f(unsigned short u) {
  return __uint_as_float(((unsigned)u) << 16);
}

// ---------------- prep: W fragments + zero bcur/ZR-row ----------------
// Fragment convention (16x16x32 bf16): lane = (idx&15) + 16*kb; element e <-> k = s*32 + kb*8 + e.
// fid = mat*16 + part*8 + s*4 + ntile; mat: 0=conv 1=res; part: 0=bf16-hi 1=bf16-lo.

__global__ __launch_bounds__(256) void k_prep(const float* __restrict__ Wc, const float* __restrict__ Wr,
                                              unsigned short* __restrict__ Wf,
                                              int* __restrict__ bcur,
                                              unsigned short* __restrict__ hWbf) {
  if (blockIdx.x == 8) {
    int tt = threadIdx.x;
    for (int i = tt; i < 1024; i += 256) bcur[i] = 0;
    if (tt < 32) ((unsigned*)(hWbf + (size_t)ZR * 64))[tt] = 0u;
    return;
  }
  int t = blockIdx.x * 256 + threadIdx.x;   // 2048 threads = 32 frags * 64 lanes
  int fid = t >> 6;
  int lane = t & 63;
  int ntile = fid & 3, s = (fid >> 2) & 1, part = (fid >> 3) & 1, mat = fid >> 4;
  const float* W = mat ? Wr : Wc;
  int col = ntile * 16 + (lane & 15);
  int k0 = s * 32 + (lane >> 4) * 8;
#pragma unroll
  for (int e = 0; e < 8; e++) {
    float w = W[(k0 + e) * 64 + col];
    unsigned short h = f2bf(w);
    Wf[(size_t)fid * 512 + lane * 8 + e] = part ? f2bf(w - bf2f(h)) : h;
  }
}

// ---------------- binning into padded buckets: colp[b*CAP + r] ----------------

__global__ __launch_bounds__(256) void k_bin(const int* __restrict__ src, const int* __restrict__ dst,
                                             int* __restrict__ bcur, int* __restrict__ colp) {
  __shared__ int hist[NBKT];
  __shared__ int gbase[NBKT];
  int t = threadIdx.x;
  for (int b = t; b < NBKT; b += 256) hist[b] = 0;
  __syncthreads();
  int e0 = blockIdx.x * 8192;
#pragma unroll
  for (int i = 0; i < 32; i++) {
    int e = e0 + i * 256 + t;
    if (e < NE) atomicAdd(&hist[dst[e] >> 6], 1);
  }
  __syncthreads();
  for (int b = t; b < NBKT; b += 256) {
    int c = hist[b];
    gbase[b] = c ? atomicAdd(&bcur[b], c) : 0;
    hist[b] = 0;  // reuse as rank counter
  }
  __syncthreads();
#pragma unroll
  for (int i = 0; i < 32; i++) {
    int e = e0 + i * 256 + t;
    if (e < NE) {
      int s = src[e], d = dst[e];
      int b = d >> 6;
      int r = atomicAdd(&hist[b], 1);
      colp[b * CAP + gbase[b] + r] = (s << 6) | (d & 63);
    }
  }
}

// ---------------- shared gemm tile body (MFMA, LDS-free, split-bf16) ----------------
// MODE 0: X = Xin. MODE 1: X = relu(Xin + dinv[n]*bf2f(gsum[n])).

template <int MODE>
__device__ __forceinline__ void gemm_tile(int lane, int n0,
                                          const float* __restrict__ Xin,
                                          const unsigned short* __restrict__ gsum,
                                          const unsigned short* __restrict__ Wf,
                                          const float* __restrict__ cb, const float* __restrict__ rb,
                                          const float* __restrict__ dinv,
                                          unsigned short* __restrict__ hWout, float* __restrict__ agg) {
  int col16 = lane & 15;
  int kb = lane >> 4;
  int nr = n0 + col16;
  int nc = nr < NN ? nr : NN - 1;   // clamp loads; garbage rows never stored
  const float* xrow = Xin + (size_t)nc * 64;
  float v0[8], v1[8];
  {
    float4 a = *(const float4*)(xrow + kb * 8);
    float4 b4 = *(const float4*)(xrow + kb * 8 + 4);
    float4 c = *(const float4*)(xrow + 32 + kb * 8);
    float4 d = *(const float4*)(xrow + 32 + kb * 8 + 4);
    v0[0] = a.x; v0[1] = a.y; v0[2] = a.z; v0[3] = a.w;
    v0[4] = b4.x; v0[5] = b4.y; v0[6] = b4.z; v0[7] = b4.w;
    v1[0] = c.x; v1[1] = c.y; v1[2] = c.z; v1[3] = c.w;
    v1[4] = d.x; v1[5] = d.y; v1[6] = d.z; v1[7] = d.w;
  }
  if (MODE) {
    float dvn = dinv[nc];
    const unsigned* grow = (const unsigned*)(gsum + (size_t)nc * 64);
    uint4 g0 = *(const uint4*)(grow + kb * 4);
    uint4 g1 = *(const uint4*)(grow + 16 + kb * 4);
    unsigned ga[4] = {g0.x, g0.y, g0.z, g0.w};
    unsigned gb[4] = {g1.x, g1.y, g1.z, g1.w};
#pragma unroll
    for (int e = 0; e < 4; e++) {
      v0[2 * e]     = fmaxf(v0[2 * e]     + dvn * bf2f((unsigned short)(ga[e] & 0xffff)), 0.f);
      v0[2 * e + 1] = fmaxf(v0[2 * e + 1] + dvn * bf2f((unsigned short)(ga[e] >> 16)), 0.f);
      v1[2 * e]     = fmaxf(v1[2 * e]     + dvn * bf2f((unsigned short)(gb[e] & 0xffff)), 0.f);
      v1[2 * e + 1] = fmaxf(v1[2 * e + 1] + dvn * bf2f((unsigned short)(gb[e] >> 16)), 0.f);
    }
  }
  bf16x8 ah0, al0, ah1, al1;
#pragma unroll
  for (int e = 0; e < 8; e++) {
    unsigned short h0 = f2bf(v0[e]);
    ah0[e] = (short)h0;
    al0[e] = (short)f2bf(v0[e] - bf2f(h0));
    unsigned short h1 = f2bf(v1[e]);
    ah1[e] = (short)h1;
    al1[e] = (short)f2bf(v1[e] - bf2f(h1));
  }

  f32x4 aC[4], aR[4];
#pragma unroll
  for (int j = 0; j < 4; j++) {
    aC[j] = (f32x4){0.f, 0.f, 0.f, 0.f};
    aR[j] = (f32x4){0.f, 0.f, 0.f, 0.f};
  }
  const bf16x8* WFv = (const bf16x8*)Wf;
#pragma unroll
  for (int j = 0; j < 4; j++) {
    bf16x8 wch0 = WFv[(j)      * 64 + lane];
    bf16x8 wch1 = WFv[(4 + j)  * 64 + lane];
    bf16x8 wcl0 = WFv[(8 + j)  * 64 + lane];
    bf16x8 wcl1 = WFv[(12 + j) * 64 + lane];
    bf16x8 wrh0 = WFv[(16 + j) * 64 + lane];
    bf16x8 wrh1 = WFv[(20 + j) * 64 + lane];
    bf16x8 wrl0 = WFv[(24 + j) * 64 + lane];
    bf16x8 wrl1 = WFv[(28 + j) * 64 + lane];
    f32x4 c = aC[j];
    c = __builtin_amdgcn_mfma_f32_16x16x32_bf16(ah0, wch0, c, 0, 0, 0);
    c = __builtin_amdgcn_mfma_f32_16x16x32_bf16(ah1, wch1, c, 0, 0, 0);
    c = __builtin_amdgcn_mfma_f32_16x16x32_bf16(al0, wch0, c, 0, 0, 0);
    c = __builtin_amdgcn_mfma_f32_16x16x32_bf16(al1, wch1, c, 0, 0, 0);
    c = __builtin_amdgcn_mfma_f32_16x16x32_bf16(ah0, wcl0, c, 0, 0, 0);
    c = __builtin_amdgcn_mfma_f32_16x16x32_bf16(ah1, wcl1, c, 0, 0, 0);
    aC[j] = c;
    f32x4 r = aR[j];
    r = __builtin_amdgcn_mfma_f32_16x16x32_bf16(ah0, wrh0, r, 0, 0, 0);
    r = __builtin_amdgcn_mfma_f32_16x16x32_bf16(ah1, wrh1, r, 0, 0, 0);
    r = __builtin_amdgcn_mfma_f32_16x16x32_bf16(al0, wrh0, r, 0, 0, 0);
    r = __builtin_amdgcn_mfma_f32_16x16x32_bf16(al1, wrh1, r, 0, 0, 0);
    r = __builtin_amdgcn_mfma_f32_16x16x32_bf16(ah0, wrl0, r, 0, 0, 0);
    r = __builtin_amdgcn_mfma_f32_16x16x32_bf16(ah1, wrl1, r, 0, 0, 0);
    aR[j] = r;
  }

  // epilogue: D layout col=lane&15, row=(lane>>4)*4+reg
  float cbv[4], rbv[4];
#pragma unroll
  for (int j = 0; j < 4; j++) {
    cbv[j] = cb[j * 16 + col16];
    rbv[j] = rb[j * 16 + col16];
  }
  int rbase = kb * 4;
#pragma unroll
  for (int r = 0; r < 4; r++) {
    int node = n0 + rbase + r;
    if (node < NN) {
      float dv = dinv[node];
      size_t o = (size_t)node * 64 + col16;
#pragma unroll
      for (int j = 0; j < 4; j++) {
        float hc = dv * aC[j][r];
        unsigned short hb = f2bf(hc);
        hWout[o + j * 16] = hb;
        agg[o + j * 16] = aR[j][r] + rbv[j] + cbv[j] + dv * hc;
      }
    }
  }
}

// ---------------- fused: bucket CSR + gptr + encoder + gemm0 (block b = bucket b) ----------------

__global__ __launch_bounds__(256) void k_csr_enc_g0(const int* __restrict__ bcur, const int* __restrict__ colp,
                                                    int* __restrict__ cols, float* __restrict__ dinv,
                                                    int* __restrict__ rowst, int* __restrict__ rowen,
                                                    const int* __restrict__ batch, int* __restrict__ gptr,
                                                    const float* __restrict__ x, const float* __restrict__ pos,
                                                    const float* __restrict__ encW, const float* __restrict__ encb,
                                                    const unsigned short* __restrict__ Wf,
                                                    const float* __restrict__ cb, const float* __restrict__ rb,
                                                    unsigned short* __restrict__ hWout,
                                                    float* __restrict__ X0, float* __restrict__ agg) {
  __shared__ int hist[64];
  __shared__ int excl[65];
  __shared__ float Ws[16 * 64];
  __shared__ float bs[64];
  int t = threadIdx.x;
  int b = blockIdx.x;

  // folded gptr: graph segment pointers from sorted batch (independent work)
  int tid = b * 256 + t;
  if (tid < NN) {
    int bi = batch[tid];
    int bp = (tid > 0) ? batch[tid - 1] : -1;
    for (int g = bp + 1; g <= bi; g++) gptr[g] = tid;
    if (tid == NN - 1) {
      for (int g = bi + 1; g <= NG; g++) gptr[g] = NN;
    }
  }

  for (int i = t; i < 1024; i += 256) Ws[i] = encW[i];
  if (t < 64) bs[t] = encb[t];

  int base = b * CAP;
  int cnt = bcur[b];
  if (t < 64) hist[t] = 0;
  __syncthreads();
  for (int e = t; e < cnt; e += 256) atomicAdd(&hist[colp[base + e] & 63], 1);
  __syncthreads();
  if (t == 0) {
    int run = 0;
#pragma unroll
    for (int i = 0; i < 64; i++) { excl[i] = run; run += hist[i]; }
    excl[64] = run;
  }
  __syncthreads();
  if (t < 64) {
    int n = b * 64 + t;
    rowst[n] = base + excl[t];
    rowen[n] = base + excl[t + 1];
    if (n < NN) dinv[n] = rsqrtf((float)(hist[t] + 1));  // +1 self-loop
    hist[t] = 0;  // reuse as cursor
  }
  __syncthreads();
  for (int e = t; e < cnt; e += 256) {
    int w = colp[base + e];
    int d = w & 63;
    int r = atomicAdd(&hist[d], 1);
    cols[base + excl[d] + r] = w >> 6;
  }

  // encoder for this bucket's 64 rows (disjoint from cols scatter; barrier below covers both)
  int h = t & 63;
  int nset = t >> 6;
#pragma unroll
  for (int i = 0; i < 16; i++) {
    int n = b * 64 + nset * 16 + i;
    if (n < NN) {
      const float* xr = x + n * 14;
      float acc = bs[h];
#pragma unroll
      for (int f = 0; f < 14; f++) acc += xr[f] * Ws[f * 64 + h];
      acc += pos[n * 2 + 0] * Ws[14 * 64 + h];
      acc += pos[n * 2 + 1] * Ws[15 * 64 + h];
      X0[(size_t)n * 64 + h] = acc;
    }
  }
  __syncthreads();  // X0 + dinv visible block-wide (same CU)

  // gemm0 (mode 0): 4 waves x 16 rows x 64 cols
  gemm_tile<0>(t & 63, b * 64 + (t >> 6) * 16, X0, (const unsigned short*)0, Wf, cb, rb, dinv, hWout, agg);
}

// ---------------- standalone gemm (mode 1), layers 1..4 ----------------

__global__ __launch_bounds__(256) void k_gemm(const float* __restrict__ Xin,
                                              const unsigned short* __restrict__ gsum,
                                              const unsigned short* __restrict__ Wf,
                                              const float* __restrict__ cb, const float* __restrict__ rb,
                                              const float* __restrict__ dinv,
                                              unsigned short* __restrict__ hWout, float* __restrict__ agg) {
  gemm_tile<1>(threadIdx.x & 63, blockIdx.x * 64 + (threadIdx.x >> 6) * 16,
               Xin, gsum, Wf, cb, rb, dinv, hWout, agg);
}

// ---------------- gather core: one node per wave, 8 loads in flight ----------------
// lane = (p = lane>>5, h2 = lane&31): h-pair 2*h2, 2*h2+1 of edge-pair-member p.
// NOTE: launch_bounds min-waves=2 relaxes the VGPR cap. At __launch_bounds__(256) the
// allocator squeezed the kernel into 16 VGPRs (R2/R3 counters), which physically
// serializes the 8 row-loads (no room for 8 data + addr regs) -> latency-bound gather.

__device__ __forceinline__ void gather_node(int n, int lane, int h2, int p,
                                            const int* __restrict__ rowst, const int* __restrict__ rowen,
                                            const int* __restrict__ cols, const unsigned* __restrict__ hW32,
                                            float& a0, float& a1) {
  int st = rowst[n];
  int en = rowen[n];
  int deg = en - st;
  a0 = 0.f; a1 = 0.f;
  for (int base2 = 0; base2 < deg; base2 += 64) {
    int cnt = deg - base2;
    if (cnt > 64) cnt = 64;
    int li = lane < cnt ? lane : cnt - 1;
    int colv = cols[st + base2 + li];  // one coalesced load of up to 64 indices
    for (int j = 0; j < cnt; j += 16) {
      int sx[8];
#pragma unroll
      for (int k2 = 0; k2 < 8; k2++) {
        int e = j + 2 * k2 + p;
        int s = __shfl(colv, e, 64);
        sx[k2] = e < cnt ? s : ZR;   // padding -> dedicated zero row (one hot line)
      }
      unsigned ux[8];
#pragma unroll
      for (int k2 = 0; k2 < 8; k2++) ux[k2] = hW32[(unsigned)sx[k2] * 32u + (unsigned)h2];
#pragma unroll
      for (int k2 = 0; k2 < 8; k2++) {
        a0 += __uint_as_float(ux[k2] << 16);
        a1 += __uint_as_float(ux[k2] & 0xffff0000u);
      }
    }
  }
  a0 += __shfl_down(a0, 32, 64);
  a1 += __shfl_down(a1, 32, 64);
}

// ---------------- gather layers 0..3: hW -> gsum ----------------

__global__ __launch_bounds__(256, 2) void k_gather(const int* __restrict__ rowst, const int* __restrict__ rowen,
                                                   const int* __restrict__ cols,
                                                   const unsigned short* __restrict__ hWin,
                                                   unsigned short* __restrict__ gsum) {
  int lane = threadIdx.x & 63;
  int h2 = lane & 31;
  int p = lane >> 5;
  int n = __builtin_amdgcn_readfirstlane(blockIdx.x * 4 + (threadIdx.x >> 6));
  float a0, a1;
  gather_node(n, lane, h2, p, rowst, rowen, cols, (const unsigned*)hWin, a0, a1);
  if (lane < 32)
    ((unsigned*)gsum)[(unsigned)n * 32u + (unsigned)h2] = (unsigned)f2bf(a0) | ((unsigned)f2bf(a1) << 16);
}

// ---------------- final gather + fused decode -> Xo (plain store; pooling separate) ----------------

__global__ __launch_bounds__(256, 2) void k_gather_final(const int* __restrict__ rowst, const int* __restrict__ rowen,
                                                         const int* __restrict__ cols,
                                                         const unsigned short* __restrict__ hWin,
                                                         const float* __restrict__ aggIn, const float* __restrict__ dinv,
                                                         const float* __restrict__ decW, float* __restrict__ Xo) {
  int lane = threadIdx.x & 63;
  int h2 = lane & 31;
  int p = lane >> 5;
  int n = __builtin_amdgcn_readfirstlane(blockIdx.x * 4 + (threadIdx.x >> 6));
  float a0, a1;
  gather_node(n, lane, h2, p, rowst, rowen, cols, (const unsigned*)hWin, a0, a1);
  float dv = dinv[n];
  float2 ag = *(const float2*)(aggIn + (size_t)n * 64 + h2 * 2);  // valid addr for all lanes
  float v = fmaxf(ag.x + dv * a0, 0.f) * decW[h2 * 2] + fmaxf(ag.y + dv * a1, 0.f) * decW[h2 * 2 + 1];
  v = (lane < 32) ? v : 0.f;  // upper half holds stale partials -> zero them
#pragma unroll
  for (int off = 32; off > 0; off >>= 1) v += __shfl_down(v, off, 64);
  if (lane == 0) Xo[n] = v;
}

// ---------------- graph pooling: out[g] = sum Xo[gptr[g]:gptr[g+1]] + cnt*decb ----------------

__global__ __launch_bounds__(256) void k_pool(const float* __restrict__ Xo, const int* __restrict__ gptr,
                                              const float* __restrict__ decb, float* __restrict__ out) {
  __shared__ float part[4];
  int g = blockIdx.x;
  int t = threadIdx.x;
  int st = gptr[g], en = gptr[g + 1];
  float v = 0.f;
  for (int i = st + t; i < en; i += 256) v += Xo[i];
#pragma unroll
  for (int off = 32; off > 0; off >>= 1) v += __shfl_down(v, off, 64);
  if ((t & 63) == 0) part[t >> 6] = v;
  __syncthreads();
  if (t == 0) out[g] = part[0] + part[1] + part[2] + part[3] + (float)(en - st) * decb[0];
}

// ---------------- launch: 13 dispatches ----------------

extern "C" void kernel_launch(void* const* d_in, const int* in_sizes, int n_in,
                              void* d_out, int out_size, void* d_ws, size_t ws_size,
                              hipStream_t stream) {
  (void)in_sizes; (void)n_in; (void)out_size; (void)ws_size;
  const float* x     = (const float*)d_in[0];
  const float* pos   = (const float*)d_in[1];
  const int*   ei    = (const int*)d_in[2];
  const int*   batch = (const int*)d_in[3];
  const float* encW  = (const float*)d_in[4];
  const float* encb  = (const float*)d_in[5];
  const float* convW = (const float*)d_in[6];
  const float* convb = (const float*)d_in[7];
  const float* resW  = (const float*)d_in[8];
  const float* resb  = (const float*)d_in[9];
  const float* decW  = (const float*)d_in[10];
  const float* decb  = (const float*)d_in[11];
  float* out = (float*)d_out;

  const int* src = ei;       // edge_index[0]
  const int* dst = ei + NE;  // edge_index[1]

  // workspace layout (4-byte elems)
  float*          ws    = (float*)d_ws;
  float*          dinv  = ws;                                    // [NPAD]
  int*            rowst = (int*)(ws + NPAD);                     // [NPAD]
  int*            rowen = (int*)(ws + 2 * NPAD);                 // [NPAD]
  int*            bcur  = (int*)(ws + 3 * NPAD);                 // [1024]
  int*            gptr  = bcur + 1024;                           // [NG+1]
  float*          Xo    = (float*)(gptr + 512);                  // [NPAD]
  int*            colp  = (int*)(Xo + NPAD);                     // [NBKT*CAP]
  int*            cols  = colp + NBKT * CAP;                     // [NBKT*CAP]
  unsigned short* hWbf  = (unsigned short*)(cols + NBKT * CAP);  // [NPAD*64] bf16
  unsigned short* gsum  = hWbf + (size_t)NPAD * 64;              // [NPAD*64] bf16
  float*          bufA  = (float*)(gsum + (size_t)NPAD * 64);    // [NN*NH]
  float*          bufB  = bufA + NN * NH;                        // [NN*NH]
  unsigned short* Wf    = (unsigned short*)(bufB + NN * NH);     // [32*512] bf16 frag W

  k_prep<<<9, 256, 0, stream>>>(convW, resW, Wf, bcur, hWbf);
  k_bin<<<(NE + 8191) / 8192, 256, 0, stream>>>(src, dst, bcur, colp);
  k_csr_enc_g0<<<NBKT, 256, 0, stream>>>(bcur, colp, cols, dinv, rowst, rowen, batch, gptr,
                                         x, pos, encW, encb, Wf, convb, resb,
                                         hWbf, bufA, bufB);
  // layers: gather hW_l -> gsum; gemm mode1 -> hW_{l+1}, agg ping-pong (B->A->B->A->B)
  float* aggIn = bufB;
  float* aggOut = bufA;
  for (int l = 0; l < 4; l++) {
    k_gather<<<NN / 4, 256, 0, stream>>>(rowst, rowen, cols, hWbf, gsum);
    k_gemm<<<NBKT, 256, 0, stream>>>(aggIn, gsum, Wf, convb, resb, dinv, hWbf, aggOut);
    float* tmp = aggIn; aggIn = aggOut; aggOut = tmp;
  }
  k_gather_final<<<NN / 4, 256, 0, stream>>>(rowst, rowen, cols, hWbf, aggIn, dinv, decW, Xo);
  k_pool<<<NG, 256, 0, stream>>>(Xo, gptr, decb, out);
}

// Round 5
// 274.239 us; speedup vs baseline: 1.3314x; 1.0099x over previous
//
#include <hip/hip_runtime.h>

#define NN 50000
#define NE 800000
#define NH 64
#define NG 500
#define NPAD 50176   // 196*256
#define NBKT 782     // ceil(NN/64) 64-node buckets
#define CAP 1536     // padded bucket capacity (max bucket deg ~1130; 4.5+ sigma margin)
#define ZR NN        // dedicated zero row in hWbf (zeroed once in k_prep)

typedef __attribute__((ext_vector_type(8))) short bf16x8;   // 8 bf16 = 4 VGPR (MFMA A/B frag)
typedef __attribute__((ext_vector_type(4))) float f32x4;    // MFMA C/D frag

// fp32 -> bf16 round-to-nearest-even
__device__ __forceinline__ unsigned short f2bf(float f) {
  unsigned x = __float_as_uint(f);
  unsigned r = ((x >> 16) & 1u) + 0x7fffu;
  return (unsigned short)((x + r) >> 16);
}
__device__ __forceinline__ float bf2f(unsigned short u) {
  return __uint_as_float(((unsigned)u) << 16);
}

// ---------------- prep: W fragments + zero bcur/ZR-row ----------------
// Fragment convention (16x16x32 bf16): lane = (idx&15) + 16*kb; element e <-> k = s*32 + kb*8 + e.
// fid = mat*16 + part*8 + s*4 + ntile; mat: 0=conv 1=res; part: 0=bf16-hi 1=bf16-lo.

__global__ __launch_bounds__(256) void k_prep(const float* __restrict__ Wc, const float* __restrict__ Wr,
                                              unsigned short* __restrict__ Wf,
                                              int* __restrict__ bcur,
                                              unsigned short* __restrict__ hWbf) {
  if (blockIdx.x == 8) {
    int tt = threadIdx.x;
    for (int i = tt; i < 1024; i += 256) bcur[i] = 0;
    if (tt < 32) ((unsigned*)(hWbf + (size_t)ZR * 64))[tt] = 0u;
    return;
  }
  int t = blockIdx.x * 256 + threadIdx.x;   // 2048 threads = 32 frags * 64 lanes
  int fid = t >> 6;
  int lane = t & 63;
  int ntile = fid & 3, s = (fid >> 2) & 1, part = (fid >> 3) & 1, mat = fid >> 4;
  const float* W = mat ? Wr : Wc;
  int col = ntile * 16 + (lane & 15);
  int k0 = s * 32 + (lane >> 4) * 8;
#pragma unroll
  for (int e = 0; e < 8; e++) {
    float w = W[(k0 + e) * 64 + col];
    unsigned short h = f2bf(w);
    Wf[(size_t)fid * 512 + lane * 8 + e] = part ? f2bf(w - bf2f(h)) : h;
  }
}

// ---------------- binning into padded buckets: colp[b*CAP + r] ----------------

__global__ __launch_bounds__(256) void k_bin(const int* __restrict__ src, const int* __restrict__ dst,
                                             int* __restrict__ bcur, int* __restrict__ colp) {
  __shared__ int hist[NBKT];
  __shared__ int gbase[NBKT];
  int t = threadIdx.x;
  for (int b = t; b < NBKT; b += 256) hist[b] = 0;
  __syncthreads();
  int e0 = blockIdx.x * 8192;
#pragma unroll
  for (int i = 0; i < 32; i++) {
    int e = e0 + i * 256 + t;
    if (e < NE) atomicAdd(&hist[dst[e] >> 6], 1);
  }
  __syncthreads();
  for (int b = t; b < NBKT; b += 256) {
    int c = hist[b];
    gbase[b] = c ? atomicAdd(&bcur[b], c) : 0;
    hist[b] = 0;  // reuse as rank counter
  }
  __syncthreads();
#pragma unroll
  for (int i = 0; i < 32; i++) {
    int e = e0 + i * 256 + t;
    if (e < NE) {
      int s = src[e], d = dst[e];
      int b = d >> 6;
      int r = atomicAdd(&hist[b], 1);
      colp[b * CAP + gbase[b] + r] = (s << 6) | (d & 63);
    }
  }
}

// ---------------- shared gemm tile body (MFMA, LDS-free, split-bf16) ----------------
// MODE 0: X = Xin. MODE 1: X = relu(Xin + dinv[n]*bf2f(gsum[n])).

template <int MODE>
__device__ __forceinline__ void gemm_tile(int lane, int n0,
                                          const float* __restrict__ Xin,
                                          const unsigned short* __restrict__ gsum,
                                          const unsigned short* __restrict__ Wf,
                                          const float* __restrict__ cb, const float* __restrict__ rb,
                                          const float* __restrict__ dinv,
                                          unsigned short* __restrict__ hWout, float* __restrict__ agg) {
  int col16 = lane & 15;
  int kb = lane >> 4;
  int nr = n0 + col16;
  int nc = nr < NN ? nr : NN - 1;   // clamp loads; garbage rows never stored
  const float* xrow = Xin + (size_t)nc * 64;
  float v0[8], v1[8];
  {
    float4 a = *(const float4*)(xrow + kb * 8);
    float4 b4 = *(const float4*)(xrow + kb * 8 + 4);
    float4 c = *(const float4*)(xrow + 32 + kb * 8);
    float4 d = *(const float4*)(xrow + 32 + kb * 8 + 4);
    v0[0] = a.x; v0[1] = a.y; v0[2] = a.z; v0[3] = a.w;
    v0[4] = b4.x; v0[5] = b4.y; v0[6] = b4.z; v0[7] = b4.w;
    v1[0] = c.x; v1[1] = c.y; v1[2] = c.z; v1[3] = c.w;
    v1[4] = d.x; v1[5] = d.y; v1[6] = d.z; v1[7] = d.w;
  }
  if (MODE) {
    float dvn = dinv[nc];
    const unsigned* grow = (const unsigned*)(gsum + (size_t)nc * 64);
    uint4 g0 = *(const uint4*)(grow + kb * 4);
    uint4 g1 = *(const uint4*)(grow + 16 + kb * 4);
    unsigned ga[4] = {g0.x, g0.y, g0.z, g0.w};
    unsigned gb[4] = {g1.x, g1.y, g1.z, g1.w};
#pragma unroll
    for (int e = 0; e < 4; e++) {
      v0[2 * e]     = fmaxf(v0[2 * e]     + dvn * bf2f((unsigned short)(ga[e] & 0xffff)), 0.f);
      v0[2 * e + 1] = fmaxf(v0[2 * e + 1] + dvn * bf2f((unsigned short)(ga[e] >> 16)), 0.f);
      v1[2 * e]     = fmaxf(v1[2 * e]     + dvn * bf2f((unsigned short)(gb[e] & 0xffff)), 0.f);
      v1[2 * e + 1] = fmaxf(v1[2 * e + 1] + dvn * bf2f((unsigned short)(gb[e] >> 16)), 0.f);
    }
  }
  bf16x8 ah0, al0, ah1, al1;
#pragma unroll
  for (int e = 0; e < 8; e++) {
    unsigned short h0 = f2bf(v0[e]);
    ah0[e] = (short)h0;
    al0[e] = (short)f2bf(v0[e] - bf2f(h0));
    unsigned short h1 = f2bf(v1[e]);
    ah1[e] = (short)h1;
    al1[e] = (short)f2bf(v1[e] - bf2f(h1));
  }

  f32x4 aC[4], aR[4];
#pragma unroll
  for (int j = 0; j < 4; j++) {
    aC[j] = (f32x4){0.f, 0.f, 0.f, 0.f};
    aR[j] = (f32x4){0.f, 0.f, 0.f, 0.f};
  }
  const bf16x8* WFv = (const bf16x8*)Wf;
#pragma unroll
  for (int j = 0; j < 4; j++) {
    bf16x8 wch0 = WFv[(j)      * 64 + lane];
    bf16x8 wch1 = WFv[(4 + j)  * 64 + lane];
    bf16x8 wcl0 = WFv[(8 + j)  * 64 + lane];
    bf16x8 wcl1 = WFv[(12 + j) * 64 + lane];
    bf16x8 wrh0 = WFv[(16 + j) * 64 + lane];
    bf16x8 wrh1 = WFv[(20 + j) * 64 + lane];
    bf16x8 wrl0 = WFv[(24 + j) * 64 + lane];
    bf16x8 wrl1 = WFv[(28 + j) * 64 + lane];
    f32x4 c = aC[j];
    c = __builtin_amdgcn_mfma_f32_16x16x32_bf16(ah0, wch0, c, 0, 0, 0);
    c = __builtin_amdgcn_mfma_f32_16x16x32_bf16(ah1, wch1, c, 0, 0, 0);
    c = __builtin_amdgcn_mfma_f32_16x16x32_bf16(al0, wch0, c, 0, 0, 0);
    c = __builtin_amdgcn_mfma_f32_16x16x32_bf16(al1, wch1, c, 0, 0, 0);
    c = __builtin_amdgcn_mfma_f32_16x16x32_bf16(ah0, wcl0, c, 0, 0, 0);
    c = __builtin_amdgcn_mfma_f32_16x16x32_bf16(ah1, wcl1, c, 0, 0, 0);
    aC[j] = c;
    f32x4 r = aR[j];
    r = __builtin_amdgcn_mfma_f32_16x16x32_bf16(ah0, wrh0, r, 0, 0, 0);
    r = __builtin_amdgcn_mfma_f32_16x16x32_bf16(ah1, wrh1, r, 0, 0, 0);
    r = __builtin_amdgcn_mfma_f32_16x16x32_bf16(al0, wrh0, r, 0, 0, 0);
    r = __builtin_amdgcn_mfma_f32_16x16x32_bf16(al1, wrh1, r, 0, 0, 0);
    r = __builtin_amdgcn_mfma_f32_16x16x32_bf16(ah0, wrl0, r, 0, 0, 0);
    r = __builtin_amdgcn_mfma_f32_16x16x32_bf16(ah1, wrl1, r, 0, 0, 0);
    aR[j] = r;
  }

  // epilogue: D layout col=lane&15, row=(lane>>4)*4+reg
  float cbv[4], rbv[4];
#pragma unroll
  for (int j = 0; j < 4; j++) {
    cbv[j] = cb[j * 16 + col16];
    rbv[j] = rb[j * 16 + col16];
  }
  int rbase = kb * 4;
#pragma unroll
  for (int r = 0; r < 4; r++) {
    int node = n0 + rbase + r;
    if (node < NN) {
      float dv = dinv[node];
      size_t o = (size_t)node * 64 + col16;
#pragma unroll
      for (int j = 0; j < 4; j++) {
        float hc = dv * aC[j][r];
        unsigned short hb = f2bf(hc);
        hWout[o + j * 16] = hb;
        agg[o + j * 16] = aR[j][r] + rbv[j] + cbv[j] + dv * hc;
      }
    }
  }
}

// ---------------- fused: bucket CSR + gptr + encoder + gemm0 (block b = bucket b) ----------------

__global__ __launch_bounds__(256) void k_csr_enc_g0(const int* __restrict__ bcur, const int* __restrict__ colp,
                                                    int* __restrict__ cols, float* __restrict__ dinv,
                                                    int2* __restrict__ rows2,
                                                    const int* __restrict__ batch, int* __restrict__ gptr,
                                                    const float* __restrict__ x, const float* __restrict__ pos,
                                                    const float* __restrict__ encW, const float* __restrict__ encb,
                                                    const unsigned short* __restrict__ Wf,
                                                    const float* __restrict__ cb, const float* __restrict__ rb,
                                                    unsigned short* __restrict__ hWout,
                                                    float* __restrict__ X0, float* __restrict__ agg) {
  __shared__ int hist[64];
  __shared__ int excl[65];
  __shared__ float Ws[16 * 64];
  __shared__ float bs[64];
  int t = threadIdx.x;
  int b = blockIdx.x;

  // folded gptr: graph segment pointers from sorted batch (independent work)
  int tid = b * 256 + t;
  if (tid < NN) {
    int bi = batch[tid];
    int bp = (tid > 0) ? batch[tid - 1] : -1;
    for (int g = bp + 1; g <= bi; g++) gptr[g] = tid;
    if (tid == NN - 1) {
      for (int g = bi + 1; g <= NG; g++) gptr[g] = NN;
    }
  }

  for (int i = t; i < 1024; i += 256) Ws[i] = encW[i];
  if (t < 64) bs[t] = encb[t];

  int base = b * CAP;
  int cnt = bcur[b];
  if (t < 64) hist[t] = 0;
  __syncthreads();
  for (int e = t; e < cnt; e += 256) atomicAdd(&hist[colp[base + e] & 63], 1);
  __syncthreads();
  if (t == 0) {
    int run = 0;
#pragma unroll
    for (int i = 0; i < 64; i++) { excl[i] = run; run += hist[i]; }
    excl[64] = run;
  }
  __syncthreads();
  if (t < 64) {
    int n = b * 64 + t;
    rows2[n] = make_int2(base + excl[t], base + excl[t + 1]);  // fused row metadata: 1 load in gather
    if (n < NN) dinv[n] = rsqrtf((float)(hist[t] + 1));  // +1 self-loop
    hist[t] = 0;  // reuse as cursor
  }
  __syncthreads();
  for (int e = t; e < cnt; e += 256) {
    int w = colp[base + e];
    int d = w & 63;
    int r = atomicAdd(&hist[d], 1);
    cols[base + excl[d] + r] = w >> 6;
  }

  // encoder for this bucket's 64 rows (disjoint from cols scatter; barrier below covers both)
  int h = t & 63;
  int nset = t >> 6;
#pragma unroll
  for (int i = 0; i < 16; i++) {
    int n = b * 64 + nset * 16 + i;
    if (n < NN) {
      const float* xr = x + n * 14;
      float acc = bs[h];
#pragma unroll
      for (int f = 0; f < 14; f++) acc += xr[f] * Ws[f * 64 + h];
      acc += pos[n * 2 + 0] * Ws[14 * 64 + h];
      acc += pos[n * 2 + 1] * Ws[15 * 64 + h];
      X0[(size_t)n * 64 + h] = acc;
    }
  }
  __syncthreads();  // X0 + dinv visible block-wide (same CU)

  // gemm0 (mode 0): 4 waves x 16 rows x 64 cols
  gemm_tile<0>(t & 63, b * 64 + (t >> 6) * 16, X0, (const unsigned short*)0, Wf, cb, rb, dinv, hWout, agg);
}

// ---------------- standalone gemm (mode 1), layers 1..4 ----------------

__global__ __launch_bounds__(256) void k_gemm(const float* __restrict__ Xin,
                                              const unsigned short* __restrict__ gsum,
                                              const unsigned short* __restrict__ Wf,
                                              const float* __restrict__ cb, const float* __restrict__ rb,
                                              const float* __restrict__ dinv,
                                              unsigned short* __restrict__ hWout, float* __restrict__ agg) {
  gemm_tile<1>(threadIdx.x & 63, blockIdx.x * 64 + (threadIdx.x >> 6) * 16,
               Xin, gsum, Wf, cb, rb, dinv, hWout, agg);
}

// ---------------- gather core: one node per wave, 8 loads in flight ----------------
// lane = (p = lane>>5, h2 = lane&31): h-pair 2*h2, 2*h2+1 of edge-pair-member p.
// (256,8) caps VGPR at 64 -> 32 waves/CU (R4's (256,2) left occupancy at ~60%; latency-bound
// gather scales with resident waves). 8-deep batch + 32-bit voffsets fit in ~40 VGPR.

__device__ __forceinline__ void gather_node(int n, int lane, int h2, int p,
                                            const int2* __restrict__ rows2,
                                            const int* __restrict__ cols, const unsigned* __restrict__ hW32,
                                            float& a0, float& a1) {
  int2 se = rows2[n];          // one 8-B load for {rowstart, rowend}
  int st = se.x;
  int deg = se.y - se.x;
  a0 = 0.f; a1 = 0.f;
  for (int base2 = 0; base2 < deg; base2 += 64) {
    int cnt = deg - base2;
    if (cnt > 64) cnt = 64;
    int li = lane < cnt ? lane : cnt - 1;
    int colv = cols[st + base2 + li];  // one coalesced load of up to 64 indices
    for (int j = 0; j < cnt; j += 16) {
      int sx[8];
#pragma unroll
      for (int k2 = 0; k2 < 8; k2++) {
        int e = j + 2 * k2 + p;
        int s = __shfl(colv, e, 64);
        sx[k2] = e < cnt ? s : ZR;   // padding -> dedicated zero row (one hot line)
      }
      unsigned ux[8];
#pragma unroll
      for (int k2 = 0; k2 < 8; k2++) ux[k2] = hW32[(unsigned)sx[k2] * 32u + (unsigned)h2];
#pragma unroll
      for (int k2 = 0; k2 < 8; k2++) {
        a0 += __uint_as_float(ux[k2] << 16);
        a1 += __uint_as_float(ux[k2] & 0xffff0000u);
      }
    }
  }
  a0 += __shfl_down(a0, 32, 64);
  a1 += __shfl_down(a1, 32, 64);
}

// ---------------- gather layers 0..3: hW -> gsum ----------------

__global__ __launch_bounds__(256, 8) void k_gather(const int2* __restrict__ rows2,
                                                   const int* __restrict__ cols,
                                                   const unsigned short* __restrict__ hWin,
                                                   unsigned short* __restrict__ gsum) {
  int lane = threadIdx.x & 63;
  int h2 = lane & 31;
  int p = lane >> 5;
  int n = __builtin_amdgcn_readfirstlane(blockIdx.x * 4 + (threadIdx.x >> 6));
  float a0, a1;
  gather_node(n, lane, h2, p, rows2, cols, (const unsigned*)hWin, a0, a1);
  if (lane < 32)
    ((unsigned*)gsum)[(unsigned)n * 32u + (unsigned)h2] = (unsigned)f2bf(a0) | ((unsigned)f2bf(a1) << 16);
}

// ---------------- final gather + fused decode -> Xo (plain store; pooling separate) ----------------

__global__ __launch_bounds__(256, 8) void k_gather_final(const int2* __restrict__ rows2,
                                                         const int* __restrict__ cols,
                                                         const unsigned short* __restrict__ hWin,
                                                         const float* __restrict__ aggIn, const float* __restrict__ dinv,
                                                         const float* __restrict__ decW, float* __restrict__ Xo) {
  int lane = threadIdx.x & 63;
  int h2 = lane & 31;
  int p = lane >> 5;
  int n = __builtin_amdgcn_readfirstlane(blockIdx.x * 4 + (threadIdx.x >> 6));
  float a0, a1;
  gather_node(n, lane, h2, p, rows2, cols, (const unsigned*)hWin, a0, a1);
  float dv = dinv[n];
  float2 ag = *(const float2*)(aggIn + (size_t)n * 64 + h2 * 2);  // valid addr for all lanes
  float v = fmaxf(ag.x + dv * a0, 0.f) * decW[h2 * 2] + fmaxf(ag.y + dv * a1, 0.f) * decW[h2 * 2 + 1];
  v = (lane < 32) ? v : 0.f;  // upper half holds stale partials -> zero them
#pragma unroll
  for (int off = 32; off > 0; off >>= 1) v += __shfl_down(v, off, 64);
  if (lane == 0) Xo[n] = v;
}

// ---------------- graph pooling: out[g] = sum Xo[gptr[g]:gptr[g+1]] + cnt*decb ----------------

__global__ __launch_bounds__(256) void k_pool(const float* __restrict__ Xo, const int* __restrict__ gptr,
                                              const float* __restrict__ decb, float* __restrict__ out) {
  __shared__ float part[4];
  int g = blockIdx.x;
  int t = threadIdx.x;
  int st = gptr[g], en = gptr[g + 1];
  float v = 0.f;
  for (int i = st + t; i < en; i += 256) v += Xo[i];
#pragma unroll
  for (int off = 32; off > 0; off >>= 1) v += __shfl_down(v, off, 64);
  if ((t & 63) == 0) part[t >> 6] = v;
  __syncthreads();
  if (t == 0) out[g] = part[0] + part[1] + part[2] + part[3] + (float)(en - st) * decb[0];
}

// ---------------- launch: 13 dispatches ----------------

extern "C" void kernel_launch(void* const* d_in, const int* in_sizes, int n_in,
                              void* d_out, int out_size, void* d_ws, size_t ws_size,
                              hipStream_t stream) {
  (void)in_sizes; (void)n_in; (void)out_size; (void)ws_size;
  const float* x     = (const float*)d_in[0];
  const float* pos   = (const float*)d_in[1];
  const int*   ei    = (const int*)d_in[2];
  const int*   batch = (const int*)d_in[3];
  const float* encW  = (const float*)d_in[4];
  const float* encb  = (const float*)d_in[5];
  const float* convW = (const float*)d_in[6];
  const float* convb = (const float*)d_in[7];
  const float* resW  = (const float*)d_in[8];
  const float* resb  = (const float*)d_in[9];
  const float* decW  = (const float*)d_in[10];
  const float* decb  = (const float*)d_in[11];
  float* out = (float*)d_out;

  const int* src = ei;       // edge_index[0]
  const int* dst = ei + NE;  // edge_index[1]

  // workspace layout (4-byte elems)
  float*          ws    = (float*)d_ws;
  float*          dinv  = ws;                                    // [NPAD]
  int2*           rows2 = (int2*)(ws + NPAD);                    // [NPAD] {st,en}
  int*            bcur  = (int*)(ws + 3 * NPAD);                 // [1024]
  int*            gptr  = bcur + 1024;                           // [NG+1]
  float*          Xo    = (float*)(gptr + 512);                  // [NPAD]
  int*            colp  = (int*)(Xo + NPAD);                     // [NBKT*CAP]
  int*            cols  = colp + NBKT * CAP;                     // [NBKT*CAP]
  unsigned short* hWbf  = (unsigned short*)(cols + NBKT * CAP);  // [NPAD*64] bf16
  unsigned short* gsum  = hWbf + (size_t)NPAD * 64;              // [NPAD*64] bf16
  float*          bufA  = (float*)(gsum + (size_t)NPAD * 64);    // [NN*NH]
  float*          bufB  = bufA + NN * NH;                        // [NN*NH]
  unsigned short* Wf    = (unsigned short*)(bufB + NN * NH);     // [32*512] bf16 frag W

  k_prep<<<9, 256, 0, stream>>>(convW, resW, Wf, bcur, hWbf);
  k_bin<<<(NE + 8191) / 8192, 256, 0, stream>>>(src, dst, bcur, colp);
  k_csr_enc_g0<<<NBKT, 256, 0, stream>>>(bcur, colp, cols, dinv, rows2, batch, gptr,
                                         x, pos, encW, encb, Wf, convb, resb,
                                         hWbf, bufA, bufB);
  // layers: gather hW_l -> gsum; gemm mode1 -> hW_{l+1}, agg ping-pong (B->A->B->A->B)
  float* aggIn = bufB;
  float* aggOut = bufA;
  for (int l = 0; l < 4; l++) {
    k_gather<<<NN / 4, 256, 0, stream>>>(rows2, cols, hWbf, gsum);
    k_gemm<<<NBKT, 256, 0, stream>>>(aggIn, gsum, Wf, convb, resb, dinv, hWbf, aggOut);
    float* tmp = aggIn; aggIn = aggOut; aggOut = tmp;
  }
  k_gather_final<<<NN / 4, 256, 0, stream>>>(rows2, cols, hWbf, aggIn, dinv, decW, Xo);
  k_pool<<<NG, 256, 0, stream>>>(Xo, gptr, decb, out);
}